// Round 1
// 449.217 us; speedup vs baseline: 1.0380x; 1.0380x over previous
//
#include <hip/hip_runtime.h>
#include <math.h>

#define N_NODES 50000
#define DIM     128
#define NHEAD   4
#define NCH     16
#define HC      64
#define NE      800000
#define EDIM    64
#define NEG     0.2f
#define MAXE    64

__device__ __forceinline__ float lrelu(float v) { return v > 0.f ? v : NEG * v; }

// ---------------- K1: v_edge[h][d] = sum_c att_edge[h,c] * W_edge[h*16+c, d] ----------------
__global__ void k1_vedge(const float* __restrict__ W_edge, const float* __restrict__ att_edge,
                         float* __restrict__ v_edge) {
    int t = threadIdx.x;          // 256 threads
    int h = t >> 6, d = t & 63;
    float acc = 0.f;
    #pragma unroll
    for (int c = 0; c < NCH; ++c)
        acc = fmaf(att_edge[h * NCH + c], W_edge[(h * NCH + c) * EDIM + d], acc);
    v_edge[h * 64 + d] = acc;
}

// ---------------- K2: xh = x @ W^T  [N,64]; a_src/a_dst [N,4] ----------------
__global__ __launch_bounds__(256) void k2_xh(const float* __restrict__ x, const float* __restrict__ W,
                                             const float* __restrict__ att_src, const float* __restrict__ att_dst,
                                             float* __restrict__ xh, float* __restrict__ a_src,
                                             float* __restrict__ a_dst) {
    __shared__ float Wt[128 * 68];   // Wt[k*68 + col]
    int t = threadIdx.x;
    for (int idx = t; idx < 64 * 128; idx += 256) {
        int col = idx >> 7, k = idx & 127;
        Wt[k * 68 + col] = W[idx];
    }
    __syncthreads();

    int h  = t & 3;
    int rp = t >> 2;                       // 0..63
    int row0 = blockIdx.x * 128 + rp * 2;  // this thread: rows row0, row0+1, head h
    int r0 = min(row0, N_NODES - 1);
    int r1 = min(row0 + 1, N_NODES - 1);
    const float4* x0 = (const float4*)(x + (size_t)r0 * DIM);
    const float4* x1 = (const float4*)(x + (size_t)r1 * DIM);

    float acc0[16], acc1[16];
    #pragma unroll
    for (int c = 0; c < 16; ++c) { acc0[c] = 0.f; acc1[c] = 0.f; }

    for (int k4 = 0; k4 < 32; ++k4) {
        float4 xa = x0[k4];
        float4 xb = x1[k4];
        #pragma unroll
        for (int kk = 0; kk < 4; ++kk) {
            float va = (&xa.x)[kk];
            float vb = (&xb.x)[kk];
            const float* wr = &Wt[(k4 * 4 + kk) * 68 + h * 16];
            #pragma unroll
            for (int j = 0; j < 4; ++j) {
                float4 w = *(const float4*)(wr + 4 * j);
                acc0[4 * j + 0] = fmaf(va, w.x, acc0[4 * j + 0]);
                acc0[4 * j + 1] = fmaf(va, w.y, acc0[4 * j + 1]);
                acc0[4 * j + 2] = fmaf(va, w.z, acc0[4 * j + 2]);
                acc0[4 * j + 3] = fmaf(va, w.w, acc0[4 * j + 3]);
                acc1[4 * j + 0] = fmaf(vb, w.x, acc1[4 * j + 0]);
                acc1[4 * j + 1] = fmaf(vb, w.y, acc1[4 * j + 1]);
                acc1[4 * j + 2] = fmaf(vb, w.z, acc1[4 * j + 2]);
                acc1[4 * j + 3] = fmaf(vb, w.w, acc1[4 * j + 3]);
            }
        }
    }

    if (row0 < N_NODES) {
        float4* o = (float4*)(xh + (size_t)row0 * HC + h * 16);
        o[0] = make_float4(acc0[0], acc0[1], acc0[2], acc0[3]);
        o[1] = make_float4(acc0[4], acc0[5], acc0[6], acc0[7]);
        o[2] = make_float4(acc0[8], acc0[9], acc0[10], acc0[11]);
        o[3] = make_float4(acc0[12], acc0[13], acc0[14], acc0[15]);
        float ss = 0.f, sd = 0.f;
        #pragma unroll
        for (int c = 0; c < 16; ++c) {
            ss = fmaf(acc0[c], att_src[h * 16 + c], ss);
            sd = fmaf(acc0[c], att_dst[h * 16 + c], sd);
        }
        a_src[row0 * 4 + h] = ss;
        a_dst[row0 * 4 + h] = sd;
    }
    if (row0 + 1 < N_NODES) {
        float4* o = (float4*)(xh + (size_t)(row0 + 1) * HC + h * 16);
        o[0] = make_float4(acc1[0], acc1[1], acc1[2], acc1[3]);
        o[1] = make_float4(acc1[4], acc1[5], acc1[6], acc1[7]);
        o[2] = make_float4(acc1[8], acc1[9], acc1[10], acc1[11]);
        o[3] = make_float4(acc1[12], acc1[13], acc1[14], acc1[15]);
        float ss = 0.f, sd = 0.f;
        #pragma unroll
        for (int c = 0; c < 16; ++c) {
            ss = fmaf(acc1[c], att_src[h * 16 + c], ss);
            sd = fmaf(acc1[c], att_dst[h * 16 + c], sd);
        }
        a_src[(row0 + 1) * 4 + h] = ss;
        a_dst[(row0 + 1) * 4 + h] = sd;
    }
}

// ---------------- KA: deg histogram + per-edge rank (atomic return), coalesced ----------------
__global__ __launch_bounds__(256) void ka_deg(const int* __restrict__ ei, int* __restrict__ deg,
                                              int* __restrict__ rank) {
    int e = blockIdx.x * 256 + threadIdx.x;
    if (e >= NE) return;
    rank[e] = atomicAdd(deg + ei[NE + e], 1);   // rank of edge within its dst (arbitrary order)
}

// ---------------- K4: 3-kernel exclusive scan of deg -> rowptr ----------------
__global__ void k4a_scan(const int* __restrict__ deg, int* __restrict__ tmp, int* __restrict__ bsums) {
    int t = threadIdx.x;
    int i = blockIdx.x * 256 + t;
    int v = (i < N_NODES) ? deg[i] : 0;
    int lane = t & 63, w = t >> 6;
    int xv = v;
    #pragma unroll
    for (int o = 1; o < 64; o <<= 1) {
        int y = __shfl_up(xv, o);
        if (lane >= o) xv += y;
    }
    __shared__ int wtot[4];
    if (lane == 63) wtot[w] = xv;
    __syncthreads();
    int add = 0;
    #pragma unroll
    for (int j = 0; j < 4; ++j)
        if (j < w) add += wtot[j];
    xv += add;
    if (i < N_NODES) tmp[i] = xv;            // inclusive within block
    if (t == 255) bsums[blockIdx.x] = xv;    // block total
}

__global__ void k4b_scan(int* __restrict__ bsums, int nb) {
    int t = threadIdx.x;
    int v = (t < nb) ? bsums[t] : 0;
    int lane = t & 63, w = t >> 6;
    int xv = v;
    #pragma unroll
    for (int o = 1; o < 64; o <<= 1) {
        int y = __shfl_up(xv, o);
        if (lane >= o) xv += y;
    }
    __shared__ int wtot[4];
    if (lane == 63) wtot[w] = xv;
    __syncthreads();
    int add = 0;
    #pragma unroll
    for (int j = 0; j < 4; ++j)
        if (j < w) add += wtot[j];
    xv += add;
    if (t < nb) bsums[t] = xv - v;           // exclusive block offset
}

__global__ void k4c_finish(const int* __restrict__ tmp, const int* __restrict__ bsums,
                           int* __restrict__ rowptr) {
    int i = blockIdx.x * 256 + threadIdx.x;
    if (i >= N_NODES) return;
    int incl = tmp[i] + bsums[i >> 8];
    rowptr[i + 1] = incl;
    if (i == 0) rowptr[0] = 0;
}

// ---------------- KP-compute: pure streaming edge projection, coalesced writes ----------------
// 16 lanes per edge, 4 edges per wave iteration: 1KB coalesced edge_attr load,
// 64B coalesced p_tmp write. NO atomics, NO scatter — should run at HBM BW.
__global__ __launch_bounds__(256) void kp_compute(const float* __restrict__ edge_attr,
                                                  const float* __restrict__ v_edge,
                                                  float* __restrict__ p_tmp) {
    int lane = threadIdx.x & 63;
    int q = lane & 15;          // feature quarter 0..15 (features q*4..q*4+3)
    float4 w0 = *(const float4*)(v_edge + 0 * 64 + q * 4);
    float4 w1 = *(const float4*)(v_edge + 1 * 64 + q * 4);
    float4 w2 = *(const float4*)(v_edge + 2 * 64 + q * 4);
    float4 w3 = *(const float4*)(v_edge + 3 * 64 + q * 4);

    int wave   = (blockIdx.x * 256 + threadIdx.x) >> 6;
    int nwaves = gridDim.x * 4;
    for (int g = wave; g < NE / 4; g += nwaves) {
        float4 v = *(const float4*)(edge_attr + (size_t)g * 256 + lane * 4);
        float p0 = fmaf(v.x, w0.x, fmaf(v.y, w0.y, fmaf(v.z, w0.z, v.w * w0.w)));
        float p1 = fmaf(v.x, w1.x, fmaf(v.y, w1.y, fmaf(v.z, w1.z, v.w * w1.w)));
        float p2 = fmaf(v.x, w2.x, fmaf(v.y, w2.y, fmaf(v.z, w2.z, v.w * w2.w)));
        float p3 = fmaf(v.x, w3.x, fmaf(v.y, w3.y, fmaf(v.z, w3.z, v.w * w3.w)));
        #pragma unroll
        for (int m = 1; m < 16; m <<= 1) {
            p0 += __shfl_xor(p0, m);
            p1 += __shfl_xor(p1, m);
            p2 += __shfl_xor(p2, m);
            p3 += __shfl_xor(p3, m);
        }
        if (q == 0) {
            int e = g * 4 + (lane >> 4);
            *(float4*)(p_tmp + (size_t)e * 4) = make_float4(p0, p1, p2, p3);
        }
    }
}

// ---------------- KP-perm: atomics-free permutation scatter (4B/edge payload) ----------------
// pos = rowptr[dst] + rank[e]; rank came free from ka_deg's atomic return.
// All 64 lanes scatter in parallel; payload is just the edge id.
__global__ __launch_bounds__(256) void kp_perm(const int* __restrict__ ei,
                                               const int* __restrict__ rank,
                                               const int* __restrict__ rowptr,
                                               int* __restrict__ perm) {
    int e = blockIdx.x * 256 + threadIdx.x;
    if (e >= NE) return;
    int dst = ei[NE + e];
    perm[rowptr[dst] + rank[e]] = e;
}

// ---------------- K6: wave per node, perm-gather + LDS staging ----------------
__global__ __launch_bounds__(256) void k6_agg(const int* __restrict__ rowptr,
                                              const int* __restrict__ perm,
                                              const int* __restrict__ ei,
                                              const float* __restrict__ p_tmp,
                                              const float* __restrict__ xh,
                                              const float* __restrict__ a_src,
                                              const float* __restrict__ a_dst,
                                              const float* __restrict__ bias,
                                              float* __restrict__ out) {
    __shared__ __align__(16) float s_w[4][MAXE][4];
    __shared__ int s_src[4][MAXE];
    int wid  = threadIdx.x >> 6;
    int lane = threadIdx.x & 63;
    int n = blockIdx.x * 4 + wid;          // N_NODES % 4 == 0: all waves valid, barriers safe
    int start = rowptr[n], end = rowptr[n + 1];
    int degn = end - start;
    int m = min(degn, MAXE);

    // phase 0: stage this node's edge slice into LDS.
    // perm read is contiguous; ei / p_tmp gathers hit L2/L3 (3.2 / 12.8 MB resident arrays)
    for (int i = lane; i < m; i += 64) {
        int e = perm[start + i];
        s_src[wid][i] = ei[e];
        *(float4*)&s_w[wid][i][0] = *(const float4*)(p_tmp + (size_t)e * 4);
    }
    __syncthreads();

    // phase 1: per-head exp-weight sum + raw-p sum.  lane = slot*4 + h
    int h = lane & 3;
    float adh = a_dst[n * 4 + h];
    float sw = 0.f, sp = 0.f;
    for (int i = lane >> 2; i < m; i += 16) {
        int s   = s_src[wid][i];
        float p = s_w[wid][i][h];
        float w = __expf(lrelu(a_src[(size_t)s * 4 + h] + adh + p));
        s_w[wid][i][h] = w;                // overwrite p with w for phase 2
        sw += w;
        sp += p;
    }
    for (int i = MAXE + (lane >> 2); i < degn; i += 16) {   // overflow (deg>64): ~never
        int e = perm[start + i];
        int s = ei[e];
        float p = p_tmp[(size_t)e * 4 + h];
        sw += __expf(lrelu(a_src[(size_t)s * 4 + h] + adh + p));
        sp += p;
    }
    sw += __shfl_xor(sw, 4);  sp += __shfl_xor(sp, 4);
    sw += __shfl_xor(sw, 8);  sp += __shfl_xor(sp, 8);
    sw += __shfl_xor(sw, 16); sp += __shfl_xor(sp, 16);
    sw += __shfl_xor(sw, 32); sp += __shfl_xor(sp, 32);

    float al    = sp / fmaxf((float)degn, 1.f);
    float wself = __expf(lrelu(a_src[n * 4 + h] + adh + al));
    float denom = sw + wself + 1e-16f;
    __syncthreads();                        // s_w writes visible before phase 2

    // phase 2: accumulate. lane = h2*16 + c
    int h2 = lane >> 4;
    float d2   = __shfl(denom, h2);
    float ws2  = __shfl(wself, h2);
    float adh2 = __shfl(adh, h2);
    float acc = ws2 * xh[(size_t)n * HC + lane];

    int i = 0;
    for (; i + 4 <= m; i += 4) {
        int s0 = s_src[wid][i], s1 = s_src[wid][i + 1];
        int s2 = s_src[wid][i + 2], s3 = s_src[wid][i + 3];
        float w0 = s_w[wid][i][h2],     w1 = s_w[wid][i + 1][h2];
        float w2 = s_w[wid][i + 2][h2], w3 = s_w[wid][i + 3][h2];
        float x0 = xh[(size_t)s0 * HC + lane];
        float x1 = xh[(size_t)s1 * HC + lane];
        float x2 = xh[(size_t)s2 * HC + lane];
        float x3 = xh[(size_t)s3 * HC + lane];
        acc = fmaf(w0, x0, acc);
        acc = fmaf(w1, x1, acc);
        acc = fmaf(w2, x2, acc);
        acc = fmaf(w3, x3, acc);
    }
    for (; i < m; ++i) {
        int s = s_src[wid][i];
        acc = fmaf(s_w[wid][i][h2], xh[(size_t)s * HC + lane], acc);
    }
    for (int j = MAXE; j < degn; ++j) {     // overflow: recompute from gathered arrays
        int e = perm[start + j];
        int s = ei[e];
        float p = p_tmp[(size_t)e * 4 + h2];
        float w = __expf(lrelu(a_src[(size_t)s * 4 + h2] + adh2 + p));
        acc = fmaf(w, xh[(size_t)s * HC + lane], acc);
    }
    out[(size_t)n * HC + lane] = acc / d2 + bias[lane];
}

// ---------------- launcher ----------------
extern "C" void kernel_launch(void* const* d_in, const int* in_sizes, int n_in,
                              void* d_out, int out_size, void* d_ws, size_t ws_size,
                              hipStream_t stream) {
    const float* x         = (const float*)d_in[0];
    const int*   ei        = (const int*)d_in[1];
    const float* edge_attr = (const float*)d_in[2];
    const float* W         = (const float*)d_in[3];
    const float* W_edge    = (const float*)d_in[4];
    const float* att_src   = (const float*)d_in[5];
    const float* att_dst   = (const float*)d_in[6];
    const float* att_edge  = (const float*)d_in[7];
    const float* bias      = (const float*)d_in[8];
    float* out = (float*)d_out;

    char* ws = (char*)d_ws;
    size_t off = 0;
    float* v_edge    = (float*)(ws + off); off += 1024;                      // 256 f
    float* xh        = (float*)(ws + off); off += (size_t)N_NODES * HC * 4;  // 12.8 MB
    float* a_src     = (float*)(ws + off); off += (size_t)N_NODES * 4 * 4;
    float* a_dst     = (float*)(ws + off); off += (size_t)N_NODES * 4 * 4;
    int*   deg       = (int*)(ws + off);   off += (size_t)N_NODES * 4;
    int*   tmp       = (int*)(ws + off);   off += (size_t)N_NODES * 4;
    int*   bsums     = (int*)(ws + off);   off += 1024;
    int*   rowptr    = (int*)(ws + off);   off += (size_t)(N_NODES + 4) * 4;
    int*   rank      = (int*)(ws + off);   off += (size_t)NE * 4;            // 3.2 MB
    int*   perm      = (int*)(ws + off);   off += (size_t)NE * 4;            // 3.2 MB
    float* p_tmp     = (float*)(ws + off); off += (size_t)NE * 4 * 4;        // 12.8 MB

    hipMemsetAsync(deg, 0, (size_t)N_NODES * 4, stream);

    k1_vedge<<<1, 256, 0, stream>>>(W_edge, att_edge, v_edge);
    k2_xh<<<(N_NODES + 127) / 128, 256, 0, stream>>>(x, W, att_src, att_dst, xh, a_src, a_dst);
    ka_deg<<<(NE + 255) / 256, 256, 0, stream>>>(ei, deg, rank);
    int nb = (N_NODES + 255) / 256;   // 196
    k4a_scan<<<nb, 256, 0, stream>>>(deg, tmp, bsums);
    k4b_scan<<<1, 256, 0, stream>>>(bsums, nb);
    k4c_finish<<<nb, 256, 0, stream>>>(tmp, bsums, rowptr);
    kp_compute<<<2048, 256, 0, stream>>>(edge_attr, v_edge, p_tmp);
    kp_perm<<<(NE + 255) / 256, 256, 0, stream>>>(ei, rank, rowptr, perm);
    k6_agg<<<N_NODES / 4, 256, 0, stream>>>(rowptr, perm, ei, p_tmp, xh,
                                            a_src, a_dst, bias, out);
}

// Round 2
// 445.952 us; speedup vs baseline: 1.0456x; 1.0073x over previous
//
#include <hip/hip_runtime.h>
#include <math.h>

#define N_NODES 50000
#define DIM     128
#define NHEAD   4
#define NCH     16
#define HC      64
#define NE      800000
#define EDIM    64
#define NEG     0.2f
#define MAXE    64

__device__ __forceinline__ float lrelu(float v) { return v > 0.f ? v : NEG * v; }

// ---------------- K2: xh = x @ W^T  [N,64]; a_src/a_dst [N,4] ----------------
__global__ __launch_bounds__(256) void k2_xh(const float* __restrict__ x, const float* __restrict__ W,
                                             const float* __restrict__ att_src, const float* __restrict__ att_dst,
                                             float* __restrict__ xh, float* __restrict__ a_src,
                                             float* __restrict__ a_dst) {
    __shared__ float Wt[128 * 68];   // Wt[k*68 + col]
    int t = threadIdx.x;
    for (int idx = t; idx < 64 * 128; idx += 256) {
        int col = idx >> 7, k = idx & 127;
        Wt[k * 68 + col] = W[idx];
    }
    __syncthreads();

    int h  = t & 3;
    int rp = t >> 2;                       // 0..63
    int row0 = blockIdx.x * 128 + rp * 2;  // this thread: rows row0, row0+1, head h
    int r0 = min(row0, N_NODES - 1);
    int r1 = min(row0 + 1, N_NODES - 1);
    const float4* x0 = (const float4*)(x + (size_t)r0 * DIM);
    const float4* x1 = (const float4*)(x + (size_t)r1 * DIM);

    float acc0[16], acc1[16];
    #pragma unroll
    for (int c = 0; c < 16; ++c) { acc0[c] = 0.f; acc1[c] = 0.f; }

    for (int k4 = 0; k4 < 32; ++k4) {
        float4 xa = x0[k4];
        float4 xb = x1[k4];
        #pragma unroll
        for (int kk = 0; kk < 4; ++kk) {
            float va = (&xa.x)[kk];
            float vb = (&xb.x)[kk];
            const float* wr = &Wt[(k4 * 4 + kk) * 68 + h * 16];
            #pragma unroll
            for (int j = 0; j < 4; ++j) {
                float4 w = *(const float4*)(wr + 4 * j);
                acc0[4 * j + 0] = fmaf(va, w.x, acc0[4 * j + 0]);
                acc0[4 * j + 1] = fmaf(va, w.y, acc0[4 * j + 1]);
                acc0[4 * j + 2] = fmaf(va, w.z, acc0[4 * j + 2]);
                acc0[4 * j + 3] = fmaf(va, w.w, acc0[4 * j + 3]);
                acc1[4 * j + 0] = fmaf(vb, w.x, acc1[4 * j + 0]);
                acc1[4 * j + 1] = fmaf(vb, w.y, acc1[4 * j + 1]);
                acc1[4 * j + 2] = fmaf(vb, w.z, acc1[4 * j + 2]);
                acc1[4 * j + 3] = fmaf(vb, w.w, acc1[4 * j + 3]);
            }
        }
    }

    if (row0 < N_NODES) {
        float4* o = (float4*)(xh + (size_t)row0 * HC + h * 16);
        o[0] = make_float4(acc0[0], acc0[1], acc0[2], acc0[3]);
        o[1] = make_float4(acc0[4], acc0[5], acc0[6], acc0[7]);
        o[2] = make_float4(acc0[8], acc0[9], acc0[10], acc0[11]);
        o[3] = make_float4(acc0[12], acc0[13], acc0[14], acc0[15]);
        float ss = 0.f, sd = 0.f;
        #pragma unroll
        for (int c = 0; c < 16; ++c) {
            ss = fmaf(acc0[c], att_src[h * 16 + c], ss);
            sd = fmaf(acc0[c], att_dst[h * 16 + c], sd);
        }
        a_src[row0 * 4 + h] = ss;
        a_dst[row0 * 4 + h] = sd;
    }
    if (row0 + 1 < N_NODES) {
        float4* o = (float4*)(xh + (size_t)(row0 + 1) * HC + h * 16);
        o[0] = make_float4(acc1[0], acc1[1], acc1[2], acc1[3]);
        o[1] = make_float4(acc1[4], acc1[5], acc1[6], acc1[7]);
        o[2] = make_float4(acc1[8], acc1[9], acc1[10], acc1[11]);
        o[3] = make_float4(acc1[12], acc1[13], acc1[14], acc1[15]);
        float ss = 0.f, sd = 0.f;
        #pragma unroll
        for (int c = 0; c < 16; ++c) {
            ss = fmaf(acc1[c], att_src[h * 16 + c], ss);
            sd = fmaf(acc1[c], att_dst[h * 16 + c], sd);
        }
        a_src[(row0 + 1) * 4 + h] = ss;
        a_dst[(row0 + 1) * 4 + h] = sd;
    }
}

// ---------------- KA: deg histogram + per-edge rank (atomic return), coalesced ----------------
__global__ __launch_bounds__(256) void ka_deg(const int* __restrict__ ei, int* __restrict__ deg,
                                              int* __restrict__ rank) {
    int e = blockIdx.x * 256 + threadIdx.x;
    if (e >= NE) return;
    rank[e] = atomicAdd(deg + ei[NE + e], 1);   // rank of edge within its dst (arbitrary order)
}

// ---------------- K4: 3-kernel exclusive scan of deg -> rowptr ----------------
__global__ void k4a_scan(const int* __restrict__ deg, int* __restrict__ tmp, int* __restrict__ bsums) {
    int t = threadIdx.x;
    int i = blockIdx.x * 256 + t;
    int v = (i < N_NODES) ? deg[i] : 0;
    int lane = t & 63, w = t >> 6;
    int xv = v;
    #pragma unroll
    for (int o = 1; o < 64; o <<= 1) {
        int y = __shfl_up(xv, o);
        if (lane >= o) xv += y;
    }
    __shared__ int wtot[4];
    if (lane == 63) wtot[w] = xv;
    __syncthreads();
    int add = 0;
    #pragma unroll
    for (int j = 0; j < 4; ++j)
        if (j < w) add += wtot[j];
    xv += add;
    if (i < N_NODES) tmp[i] = xv;            // inclusive within block
    if (t == 255) bsums[blockIdx.x] = xv;    // block total
}

__global__ void k4b_scan(int* __restrict__ bsums, int nb) {
    int t = threadIdx.x;
    int v = (t < nb) ? bsums[t] : 0;
    int lane = t & 63, w = t >> 6;
    int xv = v;
    #pragma unroll
    for (int o = 1; o < 64; o <<= 1) {
        int y = __shfl_up(xv, o);
        if (lane >= o) xv += y;
    }
    __shared__ int wtot[4];
    if (lane == 63) wtot[w] = xv;
    __syncthreads();
    int add = 0;
    #pragma unroll
    for (int j = 0; j < 4; ++j)
        if (j < w) add += wtot[j];
    xv += add;
    if (t < nb) bsums[t] = xv - v;           // exclusive block offset
}

__global__ void k4c_finish(const int* __restrict__ tmp, const int* __restrict__ bsums,
                           int* __restrict__ rowptr) {
    int i = blockIdx.x * 256 + threadIdx.x;
    if (i >= N_NODES) return;
    int incl = tmp[i] + bsums[i >> 8];
    rowptr[i + 1] = incl;
    if (i == 0) rowptr[0] = 0;
}

// ---------------- KP-compute: pure streaming edge projection, coalesced writes ----------------
// k1 folded in: each block recomputes v_edge (1 KB) in LDS — 16 FMA/thread, saves a launch.
// 16 lanes per edge, 4 edges per wave iteration: 1KB coalesced edge_attr load,
// 64B coalesced p_tmp write. NO atomics, NO scatter — runs at HBM BW.
__global__ __launch_bounds__(256) void kp_compute(const float* __restrict__ edge_attr,
                                                  const float* __restrict__ W_edge,
                                                  const float* __restrict__ att_edge,
                                                  float* __restrict__ p_tmp) {
    __shared__ __align__(16) float sv[256];
    int t = threadIdx.x;
    {
        int h = t >> 6, d = t & 63;
        float acc = 0.f;
        #pragma unroll
        for (int c = 0; c < NCH; ++c)
            acc = fmaf(att_edge[h * NCH + c], W_edge[(h * NCH + c) * EDIM + d], acc);
        sv[h * 64 + d] = acc;
    }
    __syncthreads();

    int lane = t & 63;
    int q = lane & 15;          // feature quarter 0..15 (features q*4..q*4+3)
    float4 w0 = *(const float4*)(sv + 0 * 64 + q * 4);
    float4 w1 = *(const float4*)(sv + 1 * 64 + q * 4);
    float4 w2 = *(const float4*)(sv + 2 * 64 + q * 4);
    float4 w3 = *(const float4*)(sv + 3 * 64 + q * 4);

    int wave   = (blockIdx.x * 256 + t) >> 6;
    int nwaves = gridDim.x * 4;
    for (int g = wave; g < NE / 4; g += nwaves) {
        float4 v = *(const float4*)(edge_attr + (size_t)g * 256 + lane * 4);
        float p0 = fmaf(v.x, w0.x, fmaf(v.y, w0.y, fmaf(v.z, w0.z, v.w * w0.w)));
        float p1 = fmaf(v.x, w1.x, fmaf(v.y, w1.y, fmaf(v.z, w1.z, v.w * w1.w)));
        float p2 = fmaf(v.x, w2.x, fmaf(v.y, w2.y, fmaf(v.z, w2.z, v.w * w2.w)));
        float p3 = fmaf(v.x, w3.x, fmaf(v.y, w3.y, fmaf(v.z, w3.z, v.w * w3.w)));
        #pragma unroll
        for (int m = 1; m < 16; m <<= 1) {
            p0 += __shfl_xor(p0, m);
            p1 += __shfl_xor(p1, m);
            p2 += __shfl_xor(p2, m);
            p3 += __shfl_xor(p3, m);
        }
        if (q == 0) {
            int e = g * 4 + (lane >> 4);
            *(float4*)(p_tmp + (size_t)e * 4) = make_float4(p0, p1, p2, p3);
        }
    }
}

// ---------------- KP-scatter: atomic-free CSR materialization ----------------
// One thread per edge, every lane scatters in parallel. All reads coalesced
// (rank, ei, p_tmp float4); pos = rowptr[dst] + rank[e] — no cursor, no atomics,
// no streaming loop to throttle. k6 then stages fully contiguously.
__global__ __launch_bounds__(256) void kp_scatter(const int* __restrict__ ei,
                                                  const int* __restrict__ rank,
                                                  const int* __restrict__ rowptr,
                                                  const float* __restrict__ p_tmp,
                                                  int* __restrict__ csr_src,
                                                  float* __restrict__ csr_p) {
    int e = blockIdx.x * 256 + threadIdx.x;
    if (e >= NE) return;
    int dst = ei[NE + e];
    int pos = rowptr[dst] + rank[e];
    float4 p = *(const float4*)(p_tmp + (size_t)e * 4);
    csr_src[pos] = ei[e];
    *(float4*)(csr_p + (size_t)pos * 4) = p;
}

// ---------------- K6: wave per node, contiguous CSR + LDS staging ----------------
__global__ __launch_bounds__(256) void k6_agg(const int* __restrict__ rowptr,
                                              const int* __restrict__ csr_src,
                                              const float* __restrict__ csr_p,
                                              const float* __restrict__ xh,
                                              const float* __restrict__ a_src,
                                              const float* __restrict__ a_dst,
                                              const float* __restrict__ bias,
                                              float* __restrict__ out) {
    __shared__ __align__(16) float s_w[4][MAXE][4];
    __shared__ int s_src[4][MAXE];
    int wid  = threadIdx.x >> 6;
    int lane = threadIdx.x & 63;
    int n = blockIdx.x * 4 + wid;          // N_NODES % 4 == 0: all waves valid, barriers safe
    int start = rowptr[n], end = rowptr[n + 1];
    int degn = end - start;
    int m = min(degn, MAXE);

    // phase 0: stage this node's CSR slice into LDS — fully contiguous loads
    for (int i = lane; i < m; i += 64) {
        s_src[wid][i] = csr_src[start + i];
        *(float4*)&s_w[wid][i][0] = *(const float4*)(csr_p + (size_t)(start + i) * 4);
    }
    __syncthreads();

    // phase 1: per-head exp-weight sum + raw-p sum.  lane = slot*4 + h
    int h = lane & 3;
    float adh = a_dst[n * 4 + h];
    float sw = 0.f, sp = 0.f;
    for (int i = lane >> 2; i < m; i += 16) {
        int s   = s_src[wid][i];
        float p = s_w[wid][i][h];
        float w = __expf(lrelu(a_src[(size_t)s * 4 + h] + adh + p));
        s_w[wid][i][h] = w;                // overwrite p with w for phase 2
        sw += w;
        sp += p;
    }
    for (int i = MAXE + (lane >> 2); i < degn; i += 16) {   // overflow (deg>64): ~never
        int s = csr_src[start + i];
        float p = csr_p[(size_t)(start + i) * 4 + h];
        sw += __expf(lrelu(a_src[(size_t)s * 4 + h] + adh + p));
        sp += p;
    }
    sw += __shfl_xor(sw, 4);  sp += __shfl_xor(sp, 4);
    sw += __shfl_xor(sw, 8);  sp += __shfl_xor(sp, 8);
    sw += __shfl_xor(sw, 16); sp += __shfl_xor(sp, 16);
    sw += __shfl_xor(sw, 32); sp += __shfl_xor(sp, 32);

    float al    = sp / fmaxf((float)degn, 1.f);
    float wself = __expf(lrelu(a_src[n * 4 + h] + adh + al));
    float denom = sw + wself + 1e-16f;
    __syncthreads();                        // s_w writes visible before phase 2

    // phase 2: accumulate. lane = h2*16 + c
    int h2 = lane >> 4;
    float d2   = __shfl(denom, h2);
    float ws2  = __shfl(wself, h2);
    float adh2 = __shfl(adh, h2);
    float acc = ws2 * xh[(size_t)n * HC + lane];

    int i = 0;
    for (; i + 4 <= m; i += 4) {
        int s0 = s_src[wid][i], s1 = s_src[wid][i + 1];
        int s2 = s_src[wid][i + 2], s3 = s_src[wid][i + 3];
        float w0 = s_w[wid][i][h2],     w1 = s_w[wid][i + 1][h2];
        float w2 = s_w[wid][i + 2][h2], w3 = s_w[wid][i + 3][h2];
        float x0 = xh[(size_t)s0 * HC + lane];
        float x1 = xh[(size_t)s1 * HC + lane];
        float x2 = xh[(size_t)s2 * HC + lane];
        float x3 = xh[(size_t)s3 * HC + lane];
        acc = fmaf(w0, x0, acc);
        acc = fmaf(w1, x1, acc);
        acc = fmaf(w2, x2, acc);
        acc = fmaf(w3, x3, acc);
    }
    for (; i < m; ++i) {
        int s = s_src[wid][i];
        acc = fmaf(s_w[wid][i][h2], xh[(size_t)s * HC + lane], acc);
    }
    for (int j = MAXE; j < degn; ++j) {     // overflow: recompute from contiguous CSR
        int s = csr_src[start + j];
        float p = csr_p[(size_t)(start + j) * 4 + h2];
        float w = __expf(lrelu(a_src[(size_t)s * 4 + h2] + adh2 + p));
        acc = fmaf(w, xh[(size_t)s * HC + lane], acc);
    }
    out[(size_t)n * HC + lane] = acc / d2 + bias[lane];
}

// ---------------- launcher ----------------
extern "C" void kernel_launch(void* const* d_in, const int* in_sizes, int n_in,
                              void* d_out, int out_size, void* d_ws, size_t ws_size,
                              hipStream_t stream) {
    const float* x         = (const float*)d_in[0];
    const int*   ei        = (const int*)d_in[1];
    const float* edge_attr = (const float*)d_in[2];
    const float* W         = (const float*)d_in[3];
    const float* W_edge    = (const float*)d_in[4];
    const float* att_src   = (const float*)d_in[5];
    const float* att_dst   = (const float*)d_in[6];
    const float* att_edge  = (const float*)d_in[7];
    const float* bias      = (const float*)d_in[8];
    float* out = (float*)d_out;

    char* ws = (char*)d_ws;
    size_t off = 0;
    float* xh        = (float*)(ws + off); off += (size_t)N_NODES * HC * 4;  // 12.8 MB
    float* a_src     = (float*)(ws + off); off += (size_t)N_NODES * 4 * 4;
    float* a_dst     = (float*)(ws + off); off += (size_t)N_NODES * 4 * 4;
    int*   deg       = (int*)(ws + off);   off += (size_t)N_NODES * 4;
    int*   tmp       = (int*)(ws + off);   off += (size_t)N_NODES * 4;
    int*   bsums     = (int*)(ws + off);   off += 1024;
    int*   rowptr    = (int*)(ws + off);   off += (size_t)(N_NODES + 4) * 4;
    int*   rank      = (int*)(ws + off);   off += (size_t)NE * 4;            // 3.2 MB
    float* p_tmp     = (float*)(ws + off); off += (size_t)NE * 4 * 4;        // 12.8 MB
    int*   csr_src   = (int*)(ws + off);   off += (size_t)NE * 4;            // 3.2 MB
    float* csr_p     = (float*)(ws + off); off += (size_t)NE * 4 * 4;        // 12.8 MB

    hipMemsetAsync(deg, 0, (size_t)N_NODES * 4, stream);

    k2_xh<<<(N_NODES + 127) / 128, 256, 0, stream>>>(x, W, att_src, att_dst, xh, a_src, a_dst);
    ka_deg<<<(NE + 255) / 256, 256, 0, stream>>>(ei, deg, rank);
    int nb = (N_NODES + 255) / 256;   // 196
    k4a_scan<<<nb, 256, 0, stream>>>(deg, tmp, bsums);
    k4b_scan<<<1, 256, 0, stream>>>(bsums, nb);
    k4c_finish<<<nb, 256, 0, stream>>>(tmp, bsums, rowptr);
    kp_compute<<<2048, 256, 0, stream>>>(edge_attr, W_edge, att_edge, p_tmp);
    kp_scatter<<<(NE + 255) / 256, 256, 0, stream>>>(ei, rank, rowptr, p_tmp, csr_src, csr_p);
    k6_agg<<<N_NODES / 4, 256, 0, stream>>>(rowptr, csr_src, csr_p, xh,
                                            a_src, a_dst, bias, out);
}

// Round 3
// 432.450 us; speedup vs baseline: 1.0783x; 1.0312x over previous
//
#include <hip/hip_runtime.h>
#include <math.h>

#define N_NODES 50000
#define DIM     128
#define NHEAD   4
#define NCH     16
#define HC      64
#define NE      800000
#define EDIM    64
#define NEG     0.2f
#define MAXE    64

__device__ __forceinline__ float lrelu(float v) { return v > 0.f ? v : NEG * v; }

// ---------------- K2: xh = x @ W^T  [N,64]; a_src/a_dst [N,4] ----------------
__global__ __launch_bounds__(256) void k2_xh(const float* __restrict__ x, const float* __restrict__ W,
                                             const float* __restrict__ att_src, const float* __restrict__ att_dst,
                                             float* __restrict__ xh, float* __restrict__ a_src,
                                             float* __restrict__ a_dst) {
    __shared__ float Wt[128 * 68];   // Wt[k*68 + col]
    int t = threadIdx.x;
    for (int idx = t; idx < 64 * 128; idx += 256) {
        int col = idx >> 7, k = idx & 127;
        Wt[k * 68 + col] = W[idx];
    }
    __syncthreads();

    int h  = t & 3;
    int rp = t >> 2;                       // 0..63
    int row0 = blockIdx.x * 128 + rp * 2;  // this thread: rows row0, row0+1, head h
    int r0 = min(row0, N_NODES - 1);
    int r1 = min(row0 + 1, N_NODES - 1);
    const float4* x0 = (const float4*)(x + (size_t)r0 * DIM);
    const float4* x1 = (const float4*)(x + (size_t)r1 * DIM);

    float acc0[16], acc1[16];
    #pragma unroll
    for (int c = 0; c < 16; ++c) { acc0[c] = 0.f; acc1[c] = 0.f; }

    for (int k4 = 0; k4 < 32; ++k4) {
        float4 xa = x0[k4];
        float4 xb = x1[k4];
        #pragma unroll
        for (int kk = 0; kk < 4; ++kk) {
            float va = (&xa.x)[kk];
            float vb = (&xb.x)[kk];
            const float* wr = &Wt[(k4 * 4 + kk) * 68 + h * 16];
            #pragma unroll
            for (int j = 0; j < 4; ++j) {
                float4 w = *(const float4*)(wr + 4 * j);
                acc0[4 * j + 0] = fmaf(va, w.x, acc0[4 * j + 0]);
                acc0[4 * j + 1] = fmaf(va, w.y, acc0[4 * j + 1]);
                acc0[4 * j + 2] = fmaf(va, w.z, acc0[4 * j + 2]);
                acc0[4 * j + 3] = fmaf(va, w.w, acc0[4 * j + 3]);
                acc1[4 * j + 0] = fmaf(vb, w.x, acc1[4 * j + 0]);
                acc1[4 * j + 1] = fmaf(vb, w.y, acc1[4 * j + 1]);
                acc1[4 * j + 2] = fmaf(vb, w.z, acc1[4 * j + 2]);
                acc1[4 * j + 3] = fmaf(vb, w.w, acc1[4 * j + 3]);
            }
        }
    }

    if (row0 < N_NODES) {
        float4* o = (float4*)(xh + (size_t)row0 * HC + h * 16);
        o[0] = make_float4(acc0[0], acc0[1], acc0[2], acc0[3]);
        o[1] = make_float4(acc0[4], acc0[5], acc0[6], acc0[7]);
        o[2] = make_float4(acc0[8], acc0[9], acc0[10], acc0[11]);
        o[3] = make_float4(acc0[12], acc0[13], acc0[14], acc0[15]);
        float ss = 0.f, sd = 0.f;
        #pragma unroll
        for (int c = 0; c < 16; ++c) {
            ss = fmaf(acc0[c], att_src[h * 16 + c], ss);
            sd = fmaf(acc0[c], att_dst[h * 16 + c], sd);
        }
        a_src[row0 * 4 + h] = ss;
        a_dst[row0 * 4 + h] = sd;
    }
    if (row0 + 1 < N_NODES) {
        float4* o = (float4*)(xh + (size_t)(row0 + 1) * HC + h * 16);
        o[0] = make_float4(acc1[0], acc1[1], acc1[2], acc1[3]);
        o[1] = make_float4(acc1[4], acc1[5], acc1[6], acc1[7]);
        o[2] = make_float4(acc1[8], acc1[9], acc1[10], acc1[11]);
        o[3] = make_float4(acc1[12], acc1[13], acc1[14], acc1[15]);
        float ss = 0.f, sd = 0.f;
        #pragma unroll
        for (int c = 0; c < 16; ++c) {
            ss = fmaf(acc1[c], att_src[h * 16 + c], ss);
            sd = fmaf(acc1[c], att_dst[h * 16 + c], sd);
        }
        a_src[(row0 + 1) * 4 + h] = ss;
        a_dst[(row0 + 1) * 4 + h] = sd;
    }
}

// ---------------- KA: deg histogram + per-edge rank (atomic return), coalesced ----------------
__global__ __launch_bounds__(256) void ka_deg(const int* __restrict__ ei, int* __restrict__ deg,
                                              int* __restrict__ rank) {
    int e = blockIdx.x * 256 + threadIdx.x;
    if (e >= NE) return;
    rank[e] = atomicAdd(deg + ei[NE + e], 1);   // rank of edge within its dst (arbitrary order)
}

// ---------------- K4: 3-kernel exclusive scan of deg -> rowptr ----------------
__global__ void k4a_scan(const int* __restrict__ deg, int* __restrict__ tmp, int* __restrict__ bsums) {
    int t = threadIdx.x;
    int i = blockIdx.x * 256 + t;
    int v = (i < N_NODES) ? deg[i] : 0;
    int lane = t & 63, w = t >> 6;
    int xv = v;
    #pragma unroll
    for (int o = 1; o < 64; o <<= 1) {
        int y = __shfl_up(xv, o);
        if (lane >= o) xv += y;
    }
    __shared__ int wtot[4];
    if (lane == 63) wtot[w] = xv;
    __syncthreads();
    int add = 0;
    #pragma unroll
    for (int j = 0; j < 4; ++j)
        if (j < w) add += wtot[j];
    xv += add;
    if (i < N_NODES) tmp[i] = xv;            // inclusive within block
    if (t == 255) bsums[blockIdx.x] = xv;    // block total
}

__global__ void k4b_scan(int* __restrict__ bsums, int nb) {
    int t = threadIdx.x;
    int v = (t < nb) ? bsums[t] : 0;
    int lane = t & 63, w = t >> 6;
    int xv = v;
    #pragma unroll
    for (int o = 1; o < 64; o <<= 1) {
        int y = __shfl_up(xv, o);
        if (lane >= o) xv += y;
    }
    __shared__ int wtot[4];
    if (lane == 63) wtot[w] = xv;
    __syncthreads();
    int add = 0;
    #pragma unroll
    for (int j = 0; j < 4; ++j)
        if (j < w) add += wtot[j];
    xv += add;
    if (t < nb) bsums[t] = xv - v;           // exclusive block offset
}

__global__ void k4c_finish(const int* __restrict__ tmp, const int* __restrict__ bsums,
                           int* __restrict__ rowptr) {
    int i = blockIdx.x * 256 + threadIdx.x;
    if (i >= N_NODES) return;
    int incl = tmp[i] + bsums[i >> 8];
    rowptr[i + 1] = incl;
    if (i == 0) rowptr[0] = 0;
}

// ---------------- KP: streaming edge projection fused with direct CSR write ----------------
// k1 folded in (v_edge recomputed per block in LDS). 16 lanes per edge, 4 edges per
// wave iteration: 1KB coalesced edge_attr load. Scatter is ATOMIC-FREE:
// pos = rowptr[dst] + rank[e] comes from ordinary pipelined loads (rank from ka_deg's
// atomic return), and the scattered stores are fire-and-forget — they overlap the
// 205 MB stream instead of standing alone in a separate kernel (r2: that pair = 112 us).
__global__ __launch_bounds__(256) void kp_csr2(const float* __restrict__ edge_attr,
                                               const float* __restrict__ W_edge,
                                               const float* __restrict__ att_edge,
                                               const int* __restrict__ ei,
                                               const int* __restrict__ rank,
                                               const int* __restrict__ rowptr,
                                               int* __restrict__ csr_src,
                                               float* __restrict__ csr_p) {
    __shared__ __align__(16) float sv[256];
    int t = threadIdx.x;
    {
        int h = t >> 6, d = t & 63;
        float acc = 0.f;
        #pragma unroll
        for (int c = 0; c < NCH; ++c)
            acc = fmaf(att_edge[h * NCH + c], W_edge[(h * NCH + c) * EDIM + d], acc);
        sv[h * 64 + d] = acc;
    }
    __syncthreads();

    int lane = t & 63;
    int q = lane & 15;          // feature quarter 0..15 (features q*4..q*4+3)
    float4 w0 = *(const float4*)(sv + 0 * 64 + q * 4);
    float4 w1 = *(const float4*)(sv + 1 * 64 + q * 4);
    float4 w2 = *(const float4*)(sv + 2 * 64 + q * 4);
    float4 w3 = *(const float4*)(sv + 3 * 64 + q * 4);

    int wave   = (blockIdx.x * 256 + t) >> 6;
    int nwaves = gridDim.x * 4;
    for (int g = wave; g < NE / 4; g += nwaves) {
        // issue the scatter-address loads early; they pipeline under the stream
        int src = 0, pos = 0;
        if (q == 0) {
            int e = g * 4 + (lane >> 4);
            src = ei[e];
            int dst = ei[NE + e];
            pos = rowptr[dst] + rank[e];
        }
        float4 v = *(const float4*)(edge_attr + (size_t)g * 256 + lane * 4);
        float p0 = fmaf(v.x, w0.x, fmaf(v.y, w0.y, fmaf(v.z, w0.z, v.w * w0.w)));
        float p1 = fmaf(v.x, w1.x, fmaf(v.y, w1.y, fmaf(v.z, w1.z, v.w * w1.w)));
        float p2 = fmaf(v.x, w2.x, fmaf(v.y, w2.y, fmaf(v.z, w2.z, v.w * w2.w)));
        float p3 = fmaf(v.x, w3.x, fmaf(v.y, w3.y, fmaf(v.z, w3.z, v.w * w3.w)));
        #pragma unroll
        for (int m = 1; m < 16; m <<= 1) {
            p0 += __shfl_xor(p0, m);
            p1 += __shfl_xor(p1, m);
            p2 += __shfl_xor(p2, m);
            p3 += __shfl_xor(p3, m);
        }
        if (q == 0) {
            csr_src[pos] = src;
            *(float4*)(csr_p + (size_t)pos * 4) = make_float4(p0, p1, p2, p3);
        }
    }
}

// ---------------- K6: wave per node, contiguous CSR + LDS staging ----------------
__global__ __launch_bounds__(256) void k6_agg(const int* __restrict__ rowptr,
                                              const int* __restrict__ csr_src,
                                              const float* __restrict__ csr_p,
                                              const float* __restrict__ xh,
                                              const float* __restrict__ a_src,
                                              const float* __restrict__ a_dst,
                                              const float* __restrict__ bias,
                                              float* __restrict__ out) {
    __shared__ __align__(16) float s_w[4][MAXE][4];
    __shared__ int s_src[4][MAXE];
    int wid  = threadIdx.x >> 6;
    int lane = threadIdx.x & 63;
    int n = blockIdx.x * 4 + wid;          // N_NODES % 4 == 0: all waves valid, barriers safe
    int start = rowptr[n], end = rowptr[n + 1];
    int degn = end - start;
    int m = min(degn, MAXE);

    // phase 0: stage this node's CSR slice into LDS — fully contiguous loads
    for (int i = lane; i < m; i += 64) {
        s_src[wid][i] = csr_src[start + i];
        *(float4*)&s_w[wid][i][0] = *(const float4*)(csr_p + (size_t)(start + i) * 4);
    }
    __syncthreads();

    // phase 1: per-head exp-weight sum + raw-p sum.  lane = slot*4 + h
    int h = lane & 3;
    float adh = a_dst[n * 4 + h];
    float sw = 0.f, sp = 0.f;
    for (int i = lane >> 2; i < m; i += 16) {
        int s   = s_src[wid][i];
        float p = s_w[wid][i][h];
        float w = __expf(lrelu(a_src[(size_t)s * 4 + h] + adh + p));
        s_w[wid][i][h] = w;                // overwrite p with w for phase 2
        sw += w;
        sp += p;
    }
    for (int i = MAXE + (lane >> 2); i < degn; i += 16) {   // overflow (deg>64): ~never
        int s = csr_src[start + i];
        float p = csr_p[(size_t)(start + i) * 4 + h];
        sw += __expf(lrelu(a_src[(size_t)s * 4 + h] + adh + p));
        sp += p;
    }
    sw += __shfl_xor(sw, 4);  sp += __shfl_xor(sp, 4);
    sw += __shfl_xor(sw, 8);  sp += __shfl_xor(sp, 8);
    sw += __shfl_xor(sw, 16); sp += __shfl_xor(sp, 16);
    sw += __shfl_xor(sw, 32); sp += __shfl_xor(sp, 32);

    float al    = sp / fmaxf((float)degn, 1.f);
    float wself = __expf(lrelu(a_src[n * 4 + h] + adh + al));
    float denom = sw + wself + 1e-16f;
    __syncthreads();                        // s_w writes visible before phase 2

    // phase 2: accumulate. lane = h2*16 + c
    int h2 = lane >> 4;
    float d2   = __shfl(denom, h2);
    float ws2  = __shfl(wself, h2);
    float adh2 = __shfl(adh, h2);
    float acc = ws2 * xh[(size_t)n * HC + lane];

    int i = 0;
    for (; i + 4 <= m; i += 4) {
        int s0 = s_src[wid][i], s1 = s_src[wid][i + 1];
        int s2 = s_src[wid][i + 2], s3 = s_src[wid][i + 3];
        float w0 = s_w[wid][i][h2],     w1 = s_w[wid][i + 1][h2];
        float w2 = s_w[wid][i + 2][h2], w3 = s_w[wid][i + 3][h2];
        float x0 = xh[(size_t)s0 * HC + lane];
        float x1 = xh[(size_t)s1 * HC + lane];
        float x2 = xh[(size_t)s2 * HC + lane];
        float x3 = xh[(size_t)s3 * HC + lane];
        acc = fmaf(w0, x0, acc);
        acc = fmaf(w1, x1, acc);
        acc = fmaf(w2, x2, acc);
        acc = fmaf(w3, x3, acc);
    }
    for (; i < m; ++i) {
        int s = s_src[wid][i];
        acc = fmaf(s_w[wid][i][h2], xh[(size_t)s * HC + lane], acc);
    }
    for (int j = MAXE; j < degn; ++j) {     // overflow: recompute from contiguous CSR
        int s = csr_src[start + j];
        float p = csr_p[(size_t)(start + j) * 4 + h2];
        float w = __expf(lrelu(a_src[(size_t)s * 4 + h2] + adh2 + p));
        acc = fmaf(w, xh[(size_t)s * HC + lane], acc);
    }
    out[(size_t)n * HC + lane] = acc / d2 + bias[lane];
}

// ---------------- launcher ----------------
extern "C" void kernel_launch(void* const* d_in, const int* in_sizes, int n_in,
                              void* d_out, int out_size, void* d_ws, size_t ws_size,
                              hipStream_t stream) {
    const float* x         = (const float*)d_in[0];
    const int*   ei        = (const int*)d_in[1];
    const float* edge_attr = (const float*)d_in[2];
    const float* W         = (const float*)d_in[3];
    const float* W_edge    = (const float*)d_in[4];
    const float* att_src   = (const float*)d_in[5];
    const float* att_dst   = (const float*)d_in[6];
    const float* att_edge  = (const float*)d_in[7];
    const float* bias      = (const float*)d_in[8];
    float* out = (float*)d_out;

    char* ws = (char*)d_ws;
    size_t off = 0;
    float* xh        = (float*)(ws + off); off += (size_t)N_NODES * HC * 4;  // 12.8 MB
    float* a_src     = (float*)(ws + off); off += (size_t)N_NODES * 4 * 4;
    float* a_dst     = (float*)(ws + off); off += (size_t)N_NODES * 4 * 4;
    int*   deg       = (int*)(ws + off);   off += (size_t)N_NODES * 4;
    int*   tmp       = (int*)(ws + off);   off += (size_t)N_NODES * 4;
    int*   bsums     = (int*)(ws + off);   off += 1024;
    int*   rowptr    = (int*)(ws + off);   off += (size_t)(N_NODES + 4) * 4;
    int*   rank      = (int*)(ws + off);   off += (size_t)NE * 4;            // 3.2 MB
    int*   csr_src   = (int*)(ws + off);   off += (size_t)NE * 4;            // 3.2 MB
    float* csr_p     = (float*)(ws + off); off += (size_t)NE * 4 * 4;        // 12.8 MB

    hipMemsetAsync(deg, 0, (size_t)N_NODES * 4, stream);

    k2_xh<<<(N_NODES + 127) / 128, 256, 0, stream>>>(x, W, att_src, att_dst, xh, a_src, a_dst);
    ka_deg<<<(NE + 255) / 256, 256, 0, stream>>>(ei, deg, rank);
    int nb = (N_NODES + 255) / 256;   // 196
    k4a_scan<<<nb, 256, 0, stream>>>(deg, tmp, bsums);
    k4b_scan<<<1, 256, 0, stream>>>(bsums, nb);
    k4c_finish<<<nb, 256, 0, stream>>>(tmp, bsums, rowptr);
    kp_csr2<<<2048, 256, 0, stream>>>(edge_attr, W_edge, att_edge, ei, rank, rowptr,
                                      csr_src, csr_p);
    k6_agg<<<N_NODES / 4, 256, 0, stream>>>(rowptr, csr_src, csr_p, xh,
                                            a_src, a_dst, bias, out);
}